// Round 2
// baseline (153.492 us; speedup 1.0000x reference)
//
#include <hip/hip_runtime.h>
#include <hip/hip_cooperative_groups.h>

namespace cg = cooperative_groups;

#define HD 64      // HIDDEN_DIM
#define VC 128     // VOCAB_SIZE
#define NS 64      // NUM_SLOTS
#define NB 256     // B
#define SL 4096    // L

__device__ __forceinline__ float wsum(float x) {
#pragma unroll
  for (int o = 32; o > 0; o >>= 1) x += __shfl_xor(x, o, 64);
  return x;
}
__device__ __forceinline__ float wmax(float x) {
#pragma unroll
  for (int o = 32; o > 0; o >>= 1) x = fmaxf(x, __shfl_xor(x, o, 64));
  return x;
}

// Kernel 1: per-vocab tables, written into the FIRST 64 KB of d_out (stash).
// HN[v][h]  = layer_norm(e + FFN(e))           (128 x 64, f32)
// WSM[v][n] = softmax(HN[v] @ gate_w + gate_b) (128 x 64, f32)
// d_ws is deliberately UNUSED by this version (probe: is ws-poison usage-conditional?)
__global__ __launch_bounds__(128) void build_tables(
    const float* __restrict__ embed, const float* __restrict__ w1, const float* __restrict__ b1,
    const float* __restrict__ w2, const float* __restrict__ b2,
    const float* __restrict__ ln_g, const float* __restrict__ ln_b,
    const float* __restrict__ gate_w, const float* __restrict__ gate_b,
    float* __restrict__ HN, float* __restrict__ WSM)
{
  const int v = blockIdx.x, t = threadIdx.x;
  __shared__ float s_e[HD], s_f1[2 * HD], s_hn[HD];

  if (t < HD) s_e[t] = embed[v * HD + t];
  __syncthreads();

  // ff1 = relu(e @ w1 + b1), one output per thread (128 outputs)
  float acc = b1[t];
#pragma unroll 8
  for (int h = 0; h < HD; ++h)
    acc = fmaf(s_e[h], w1[h * 2 * HD + t], acc);
  s_f1[t] = fmaxf(acc, 0.f);
  __syncthreads();

  // ff2 + residual + layernorm (wave 0 only: threads 0..63 = one full wave)
  if (t < HD) {
    float a2 = b2[t];
#pragma unroll 8
    for (int j = 0; j < 2 * HD; ++j)
      a2 = fmaf(s_f1[j], w2[j * HD + t], a2);
    float x = s_e[t] + a2;
    float mu = wsum(x) * (1.f / 64.f);
    float d = x - mu;
    float var = wsum(d * d) * (1.f / 64.f);
    float hn = d * rsqrtf(var + 1e-5f) * ln_g[t] + ln_b[t];
    s_hn[t] = hn;
    HN[v * HD + t] = hn;
  }
  __syncthreads();

  // gate softmax over slots (wave 0)
  if (t < NS) {
    float g = gate_b[t];
#pragma unroll 8
    for (int h = 0; h < HD; ++h)
      g = fmaf(s_hn[h], gate_w[h * NS + t], g);
    float m = wmax(g);
    float e = expf(g - m);
    float s = wsum(e);
    WSM[v * NS + t] = e / s;
  }
}

// Kernel 2 (COOPERATIVE): one block per batch, 1024 threads (16 waves).
// Reads the HN/WSM stash from d_out into LDS, grid.sync()s so every block has
// staged the tables BEFORE any block's final out-write clobbers the stash region,
// then proceeds exactly as before.
// NOTE: HN/WSM/out alias the same buffer (d_out) — no __restrict__ on them.
__global__ __launch_bounds__(1024) void batch_kernel(
    const int* __restrict__ seq, const float* HN, const float* WSM,
    const float* __restrict__ slot_keys, const float* __restrict__ out_w,
    const float* __restrict__ out_b, float* out)
{
  const int b = blockIdx.x, t = threadIdx.x;
  const int lane = t & 63, wave = t >> 6;

  __shared__ int s_cnt[VC];
  __shared__ int s_qtok;
  __align__(16) __shared__ float s_hn[VC * HD];    // 32 KB; post-GEMM reused as kA/kB
  __align__(16) __shared__ float s_wsm[VC * NS];   // 32 KB: cnt-scaled WSM (in place)
  __align__(16) __shared__ float s_keys[NS * HD];  // 16 KB
  __align__(16) __shared__ float s_part[16 * HD];  // 4 KB: ctx partials per wave
  __shared__ float s_q[HD], s_sim[NS], s_attn[NS], s_ctx[HD];

  if (t < VC) s_cnt[t] = 0;
  __syncthreads();

  // Phase 1: histogram (one int4/thread) overlapped with raw HN+WSM staging.
  const int* sb = seq + b * SL;
  const int4 sv = ((const int4*)sb)[t];          // tokens 4t .. 4t+3
  const float4 h0v = ((const float4*)HN)[t];
  const float4 h1v = ((const float4*)HN)[t + 1024];
  const float4 g0v = ((const float4*)WSM)[t];
  const float4 g1v = ((const float4*)WSM)[t + 1024];
  atomicAdd(&s_cnt[sv.x], 1);
  atomicAdd(&s_cnt[sv.y], 1);
  atomicAdd(&s_cnt[sv.z], 1);
  if (t != 1023) atomicAdd(&s_cnt[sv.w], 1);
  else s_qtok = sv.w;                            // seq[b, L-1] excluded from histogram
  ((float4*)s_hn)[t] = h0v;
  ((float4*)s_hn)[t + 1024] = h1v;
  ((float4*)s_wsm)[t] = g0v;
  ((float4*)s_wsm)[t + 1024] = g1v;
  __syncthreads();

  // Grid-wide barrier: every block has the tables in LDS; after this point the
  // stash region of d_out may be freely overwritten by final out-writes.
  cg::this_grid().sync();

  // Phase 2: scale s_wsm rows by cnt (in place, 2 float4/thread); fetch q.
  if (t < HD) s_q[t] = s_hn[s_qtok * HD + t];
  {
    float4 a = ((const float4*)s_wsm)[t];
    float4 c = ((const float4*)s_wsm)[t + 1024];
    const float c0 = (float)s_cnt[t >> 4];            // 16 float4 per 64-float row
    const float c1 = (float)s_cnt[(t + 1024) >> 4];
    a.x *= c0; a.y *= c0; a.z *= c0; a.w *= c0;
    c.x *= c1; c.y *= c1; c.z *= c1; c.w *= c1;
    ((float4*)s_wsm)[t] = a;
    ((float4*)s_wsm)[t + 1024] = c;
  }
  __syncthreads();

  // Phase 3: A += (cnt*WSM)^T @ HN, 4-way vocab split.
  // quarter qt: vocab [32qt, 32qt+32); per-thread 4x4 tile (n0..n0+4, h0..h0+4)
  const int qt = t >> 8;
  const int tid = t & 255;
  const int n0 = (tid >> 4) << 2;
  const int h0 = (tid & 15) << 2;
  const float* hb = s_hn + qt * 32 * HD;
  const float* wb = s_wsm + qt * 32 * NS;

  float accv[4][4];
  if (qt == 0) {
#pragma unroll
    for (int r = 0; r < 4; ++r) {
      const float4 sk = *(const float4*)&slot_keys[(n0 + r) * HD + h0];
      accv[r][0] = sk.x; accv[r][1] = sk.y; accv[r][2] = sk.z; accv[r][3] = sk.w;
    }
  } else {
#pragma unroll
    for (int r = 0; r < 4; ++r)
#pragma unroll
      for (int c = 0; c < 4; ++c) accv[r][c] = 0.f;
  }

#pragma unroll 4
  for (int v = 0; v < 32; ++v) {
    const float4 hv = *(const float4*)&hb[v * HD + h0];  // 16 distinct addrs/wave
    const float4 wv = *(const float4*)&wb[v * NS + n0];  // 4 distinct addrs/wave (broadcast)
    accv[0][0] = fmaf(wv.x, hv.x, accv[0][0]);
    accv[0][1] = fmaf(wv.x, hv.y, accv[0][1]);
    accv[0][2] = fmaf(wv.x, hv.z, accv[0][2]);
    accv[0][3] = fmaf(wv.x, hv.w, accv[0][3]);
    accv[1][0] = fmaf(wv.y, hv.x, accv[1][0]);
    accv[1][1] = fmaf(wv.y, hv.y, accv[1][1]);
    accv[1][2] = fmaf(wv.y, hv.z, accv[1][2]);
    accv[1][3] = fmaf(wv.y, hv.w, accv[1][3]);
    accv[2][0] = fmaf(wv.z, hv.x, accv[2][0]);
    accv[2][1] = fmaf(wv.z, hv.y, accv[2][1]);
    accv[2][2] = fmaf(wv.z, hv.z, accv[2][2]);
    accv[2][3] = fmaf(wv.z, hv.w, accv[2][3]);
    accv[3][0] = fmaf(wv.w, hv.x, accv[3][0]);
    accv[3][1] = fmaf(wv.w, hv.y, accv[3][1]);
    accv[3][2] = fmaf(wv.w, hv.z, accv[3][2]);
    accv[3][3] = fmaf(wv.w, hv.w, accv[3][3]);
  }
  __syncthreads();  // GEMM reads of s_hn/s_wsm complete; both now dead

  // Combine: kA = q0+q1, kB = q2+q3 (aliased onto s_hn), then s_keys = kA+kB.
  float* kA = s_hn;
  float* kB = s_hn + NS * HD;
  if (qt == 1) {
#pragma unroll
    for (int r = 0; r < 4; ++r) {
      float4 st; st.x = accv[r][0]; st.y = accv[r][1]; st.z = accv[r][2]; st.w = accv[r][3];
      *(float4*)&kA[(n0 + r) * HD + h0] = st;
    }
  } else if (qt == 3) {
#pragma unroll
    for (int r = 0; r < 4; ++r) {
      float4 st; st.x = accv[r][0]; st.y = accv[r][1]; st.z = accv[r][2]; st.w = accv[r][3];
      *(float4*)&kB[(n0 + r) * HD + h0] = st;
    }
  }
  __syncthreads();
  if (qt == 0) {
#pragma unroll
    for (int r = 0; r < 4; ++r) {
      float4 p = *(const float4*)&kA[(n0 + r) * HD + h0];
      p.x += accv[r][0]; p.y += accv[r][1]; p.z += accv[r][2]; p.w += accv[r][3];
      *(float4*)&kA[(n0 + r) * HD + h0] = p;
    }
  } else if (qt == 2) {
#pragma unroll
    for (int r = 0; r < 4; ++r) {
      float4 p = *(const float4*)&kB[(n0 + r) * HD + h0];
      p.x += accv[r][0]; p.y += accv[r][1]; p.z += accv[r][2]; p.w += accv[r][3];
      *(float4*)&kB[(n0 + r) * HD + h0] = p;
    }
  }
  __syncthreads();
  {
    float4 a = ((const float4*)kA)[t];   // 4096 floats = 1024 float4, one per thread
    const float4 c = ((const float4*)kB)[t];
    a.x += c.x; a.y += c.y; a.z += c.z; a.w += c.w;
    ((float4*)s_keys)[t] = a;
  }
  __syncthreads();

  // Phase 4: sim[n] — each of 16 waves owns 4 slot rows
  const float qv = s_q[lane];
  const float qn = fmaxf(sqrtf(wsum(qv * qv)), 1e-12f);
#pragma unroll
  for (int r = 0; r < 4; ++r) {
    const int n = (wave << 2) + r;
    const float kv = s_keys[n * HD + lane];
    const float kk = wsum(kv * kv);
    const float kq = wsum(kv * qv);
    if (lane == 0) s_sim[n] = kq / (fmaxf(sqrtf(kk), 1e-12f) * qn);
  }
  __syncthreads();

  // Phase 5: softmax over 64 slots (wave 0)
  if (wave == 0) {
    float svv = s_sim[lane];
    float m = wmax(svv);
    float e = expf(svv - m);
    float ssum = wsum(e);
    s_attn[lane] = e / ssum;
  }
  __syncthreads();

  // Phase 6: ctx partials — wave w covers slots [4w, 4w+4), lane = h
  {
    float c = 0.f;
#pragma unroll
    for (int r = 0; r < 4; ++r) {
      const int n = (wave << 2) + r;
      c = fmaf(s_attn[n], s_keys[n * HD + lane], c);
    }
    s_part[wave * HD + lane] = c;
  }
  __syncthreads();
  if (wave == 0) {
    float c = 0.f;
#pragma unroll
    for (int w = 0; w < 16; ++w) c += s_part[w * HD + lane];
    s_ctx[lane] = c;
  }
  __syncthreads();

  // Phase 7: out = ctx @ out_w + out_b (threads 0..127, coalesced out_w)
  if (t < VC) {
    float o = out_b[t];
#pragma unroll 8
    for (int h = 0; h < HD; ++h)
      o = fmaf(s_ctx[h], out_w[h * VC + t], o);
    out[b * VC + t] = o;
  }
}

extern "C" void kernel_launch(void* const* d_in, const int* in_sizes, int n_in,
                              void* d_out, int out_size, void* d_ws, size_t ws_size,
                              hipStream_t stream) {
  const int* seq         = (const int*)d_in[0];
  const float* embed_w   = (const float*)d_in[1];
  const float* w1        = (const float*)d_in[2];
  const float* b1        = (const float*)d_in[3];
  const float* w2        = (const float*)d_in[4];
  const float* b2        = (const float*)d_in[5];
  const float* ln_g      = (const float*)d_in[6];
  const float* ln_b      = (const float*)d_in[7];
  const float* slot_keys = (const float*)d_in[8];
  // d_in[9] = slot_vals: unused (reference sets vals = keys)
  const float* gate_w    = (const float*)d_in[10];
  const float* gate_b    = (const float*)d_in[11];
  const float* out_w     = (const float*)d_in[12];
  const float* out_b     = (const float*)d_in[13];
  float* out = (float*)d_out;

  // Stash HN/WSM (64 KB) in the first half of d_out (128 KB). d_ws is UNUSED.
  // Safety: batch_kernel grid.sync()s after staging the tables to LDS, before
  // any block's final out-write can clobber this region.
  float* HN  = (float*)d_out;      // 128*64 f32
  float* WSM = HN + VC * HD;       // 128*64 f32

  build_tables<<<VC, 128, 0, stream>>>(embed_w, w1, b1, w2, b2, ln_g, ln_b,
                                       gate_w, gate_b, HN, WSM);

  void* args[] = {(void*)&seq, (void*)&HN, (void*)&WSM, (void*)&slot_keys,
                  (void*)&out_w, (void*)&out_b, (void*)&out};
  hipLaunchCooperativeKernel((void*)batch_kernel, dim3(NB), dim3(1024),
                             args, 0, stream);
}

// Round 3
// 93.643 us; speedup vs baseline: 1.6391x; 1.6391x over previous
//
#include <hip/hip_runtime.h>

#define HD 64      // HIDDEN_DIM
#define VC 128     // VOCAB_SIZE
#define NS 64      // NUM_SLOTS
#define NB 256     // B
#define SL 4096    // L

__device__ __forceinline__ float wsum(float x) {
#pragma unroll
  for (int o = 32; o > 0; o >>= 1) x += __shfl_xor(x, o, 64);
  return x;
}
__device__ __forceinline__ float wmax(float x) {
#pragma unroll
  for (int o = 32; o > 0; o >>= 1) x = fmaxf(x, __shfl_xor(x, o, 64));
  return x;
}

// Kernel 1: per-vocab tables.
// HN[v][h]  = layer_norm(e + FFN(e))           (128 x 64, f32)
// WSM[v][n] = softmax(HN[v] @ gate_w + gate_b) (128 x 64, f32)
// All dot products use 4 independent accumulators (break serial FMA chains);
// ff2 and gate are split across both 64-thread halves + LDS pair-reduce.
__global__ __launch_bounds__(128) void build_tables(
    const float* __restrict__ embed, const float* __restrict__ w1, const float* __restrict__ b1,
    const float* __restrict__ w2, const float* __restrict__ b2,
    const float* __restrict__ ln_g, const float* __restrict__ ln_b,
    const float* __restrict__ gate_w, const float* __restrict__ gate_b,
    float* __restrict__ HN, float* __restrict__ WSM)
{
  const int v = blockIdx.x, t = threadIdx.x;
  __shared__ float s_e[HD], s_f1[2 * HD], s_hn[HD], s_red[128];

  if (t < HD) s_e[t] = embed[v * HD + t];
  __syncthreads();

  // ff1 = relu(e @ w1 + b1), one output per thread (128 outputs)
  {
    float a0 = 0.f, a1 = 0.f, a2 = 0.f, a3 = 0.f;
#pragma unroll
    for (int h = 0; h < HD; h += 4) {
      a0 = fmaf(s_e[h + 0], w1[(h + 0) * 2 * HD + t], a0);
      a1 = fmaf(s_e[h + 1], w1[(h + 1) * 2 * HD + t], a1);
      a2 = fmaf(s_e[h + 2], w1[(h + 2) * 2 * HD + t], a2);
      a3 = fmaf(s_e[h + 3], w1[(h + 3) * 2 * HD + t], a3);
    }
    s_f1[t] = fmaxf(b1[t] + ((a0 + a1) + (a2 + a3)), 0.f);
  }
  __syncthreads();

  // ff2: output col = t&63; j-range [0,128) split across the two halves
  {
    const int col = t & 63;
    const int j0 = (t >> 6) << 6;  // 0 or 64
    float a0 = 0.f, a1 = 0.f, a2 = 0.f, a3 = 0.f;
#pragma unroll
    for (int j = 0; j < 64; j += 4) {
      a0 = fmaf(s_f1[j0 + j + 0], w2[(j0 + j + 0) * HD + col], a0);
      a1 = fmaf(s_f1[j0 + j + 1], w2[(j0 + j + 1) * HD + col], a1);
      a2 = fmaf(s_f1[j0 + j + 2], w2[(j0 + j + 2) * HD + col], a2);
      a3 = fmaf(s_f1[j0 + j + 3], w2[(j0 + j + 3) * HD + col], a3);
    }
    s_red[t] = (a0 + a1) + (a2 + a3);
  }
  __syncthreads();

  // residual + layernorm (wave 0 = threads 0..63, one full wave)
  if (t < HD) {
    float x = s_e[t] + b2[t] + s_red[t] + s_red[t + 64];
    float mu = wsum(x) * (1.f / 64.f);
    float d = x - mu;
    float var = wsum(d * d) * (1.f / 64.f);
    float hn = d * rsqrtf(var + 1e-5f) * ln_g[t] + ln_b[t];
    s_hn[t] = hn;
    HN[v * HD + t] = hn;
  }
  __syncthreads();

  // gate logits: col = t&63; h-range [0,64) split across the two halves
  {
    const int col = t & 63;
    const int hh0 = (t >> 6) << 5;  // 0 or 32
    float a0 = 0.f, a1 = 0.f, a2 = 0.f, a3 = 0.f;
#pragma unroll
    for (int h = 0; h < 32; h += 4) {
      a0 = fmaf(s_hn[hh0 + h + 0], gate_w[(hh0 + h + 0) * NS + col], a0);
      a1 = fmaf(s_hn[hh0 + h + 1], gate_w[(hh0 + h + 1) * NS + col], a1);
      a2 = fmaf(s_hn[hh0 + h + 2], gate_w[(hh0 + h + 2) * NS + col], a2);
      a3 = fmaf(s_hn[hh0 + h + 3], gate_w[(hh0 + h + 3) * NS + col], a3);
    }
    s_red[t] = (a0 + a1) + (a2 + a3);
  }
  __syncthreads();

  // gate softmax over slots (wave 0)
  if (t < NS) {
    float g = gate_b[t] + s_red[t] + s_red[t + 64];
    float m = wmax(g);
    float e = expf(g - m);
    float s = wsum(e);
    WSM[v * NS + t] = e / s;
  }
}

// Kernel 2: one block per batch, 1024 threads (16 waves = 4 waves/SIMD).
// cnt[v] = histogram(seq[b, :L-1]); A = (cnt*WSM)^T @ HN; keys = slot_keys + A;
// sim = l2norm(keys) . l2norm(q); attn = softmax(sim); ctx = attn @ keys;
// out = ctx @ out_w + out_b
// GEMM split 4-way over vocab; partials combined via buffer aliased onto s_hn.
// WSM scaling by cnt happens ON the staging store (loads ride registers across
// the histogram barrier) — no separate RMW pass.
__global__ __launch_bounds__(1024) void batch_kernel(
    const int* __restrict__ seq, const float* __restrict__ HN, const float* __restrict__ WSM,
    const float* __restrict__ slot_keys, const float* __restrict__ out_w,
    const float* __restrict__ out_b, float* __restrict__ out)
{
  const int b = blockIdx.x, t = threadIdx.x;
  const int lane = t & 63, wave = t >> 6;

  __shared__ int s_cnt[VC];
  __shared__ int s_qtok;
  __align__(16) __shared__ float s_hn[VC * HD];    // 32 KB; post-GEMM reused as kA/kB
  __align__(16) __shared__ float s_wsm[VC * NS];   // 32 KB: cnt-scaled WSM
  __align__(16) __shared__ float s_keys[NS * HD];  // 16 KB
  __align__(16) __shared__ float s_part[16 * HD];  // 4 KB: ctx partials per wave
  __shared__ float s_q[HD], s_sim[NS], s_ctx[HD];

  const int qt = t >> 8;       // vocab quarter [32qt, 32qt+32)
  const int tid = t & 255;
  const int n0 = (tid >> 4) << 2;
  const int h0 = (tid & 15) << 2;

  // Early prefetch: slot_keys for the qt==0 accumulator init (hides L2 latency
  // under the histogram/staging phase).
  float4 sk0, sk1, sk2, sk3;
  if (qt == 0) {
    sk0 = *(const float4*)&slot_keys[(n0 + 0) * HD + h0];
    sk1 = *(const float4*)&slot_keys[(n0 + 1) * HD + h0];
    sk2 = *(const float4*)&slot_keys[(n0 + 2) * HD + h0];
    sk3 = *(const float4*)&slot_keys[(n0 + 3) * HD + h0];
  }

  if (t < VC) s_cnt[t] = 0;
  __syncthreads();

  // Phase 1: histogram (one int4/thread) overlapped with table loads; store HN.
  const int* sb = seq + b * SL;
  const int4 sv = ((const int4*)sb)[t];          // tokens 4t .. 4t+3
  const float4 h0v = ((const float4*)HN)[t];
  const float4 h1v = ((const float4*)HN)[t + 1024];
  const float4 g0v = ((const float4*)WSM)[t];    // held in regs across barrier
  const float4 g1v = ((const float4*)WSM)[t + 1024];
  atomicAdd(&s_cnt[sv.x], 1);
  atomicAdd(&s_cnt[sv.y], 1);
  atomicAdd(&s_cnt[sv.z], 1);
  if (t != 1023) atomicAdd(&s_cnt[sv.w], 1);
  else s_qtok = sv.w;                            // seq[b, L-1] excluded from histogram
  ((float4*)s_hn)[t] = h0v;
  ((float4*)s_hn)[t + 1024] = h1v;
  __syncthreads();                               // cnt final; s_hn ready

  // Phase 2: scale WSM by cnt on store; fetch q row.
  {
    const float c0 = (float)s_cnt[t >> 4];            // 16 float4 per 64-float row
    const float c1 = (float)s_cnt[(t + 1024) >> 4];
    float4 a = g0v, c = g1v;
    a.x *= c0; a.y *= c0; a.z *= c0; a.w *= c0;
    c.x *= c1; c.y *= c1; c.z *= c1; c.w *= c1;
    ((float4*)s_wsm)[t] = a;
    ((float4*)s_wsm)[t + 1024] = c;
  }
  if (t < HD) s_q[t] = s_hn[s_qtok * HD + t];
  __syncthreads();

  // Phase 3: A += (cnt*WSM)^T @ HN, 4-way vocab split; per-thread 4x4 tile.
  const float* hb = s_hn + qt * 32 * HD;
  const float* wb = s_wsm + qt * 32 * NS;

  float accv[4][4];
  if (qt == 0) {
    accv[0][0] = sk0.x; accv[0][1] = sk0.y; accv[0][2] = sk0.z; accv[0][3] = sk0.w;
    accv[1][0] = sk1.x; accv[1][1] = sk1.y; accv[1][2] = sk1.z; accv[1][3] = sk1.w;
    accv[2][0] = sk2.x; accv[2][1] = sk2.y; accv[2][2] = sk2.z; accv[2][3] = sk2.w;
    accv[3][0] = sk3.x; accv[3][1] = sk3.y; accv[3][2] = sk3.z; accv[3][3] = sk3.w;
  } else {
#pragma unroll
    for (int r = 0; r < 4; ++r)
#pragma unroll
      for (int c = 0; c < 4; ++c) accv[r][c] = 0.f;
  }

#pragma unroll 4
  for (int v = 0; v < 32; ++v) {
    const float4 hv = *(const float4*)&hb[v * HD + h0];  // 16 distinct addrs/wave
    const float4 wv = *(const float4*)&wb[v * NS + n0];  // 4 distinct addrs/wave (broadcast)
    accv[0][0] = fmaf(wv.x, hv.x, accv[0][0]);
    accv[0][1] = fmaf(wv.x, hv.y, accv[0][1]);
    accv[0][2] = fmaf(wv.x, hv.z, accv[0][2]);
    accv[0][3] = fmaf(wv.x, hv.w, accv[0][3]);
    accv[1][0] = fmaf(wv.y, hv.x, accv[1][0]);
    accv[1][1] = fmaf(wv.y, hv.y, accv[1][1]);
    accv[1][2] = fmaf(wv.y, hv.z, accv[1][2]);
    accv[1][3] = fmaf(wv.y, hv.w, accv[1][3]);
    accv[2][0] = fmaf(wv.z, hv.x, accv[2][0]);
    accv[2][1] = fmaf(wv.z, hv.y, accv[2][1]);
    accv[2][2] = fmaf(wv.z, hv.z, accv[2][2]);
    accv[2][3] = fmaf(wv.z, hv.w, accv[2][3]);
    accv[3][0] = fmaf(wv.w, hv.x, accv[3][0]);
    accv[3][1] = fmaf(wv.w, hv.y, accv[3][1]);
    accv[3][2] = fmaf(wv.w, hv.z, accv[3][2]);
    accv[3][3] = fmaf(wv.w, hv.w, accv[3][3]);
  }
  __syncthreads();  // GEMM reads of s_hn/s_wsm complete; both now dead

  // Combine: kA = q0+q1, kB = q2+q3 (aliased onto s_hn), then s_keys = kA+kB.
  float* kA = s_hn;
  float* kB = s_hn + NS * HD;
  if (qt == 1) {
#pragma unroll
    for (int r = 0; r < 4; ++r) {
      float4 st; st.x = accv[r][0]; st.y = accv[r][1]; st.z = accv[r][2]; st.w = accv[r][3];
      *(float4*)&kA[(n0 + r) * HD + h0] = st;
    }
  } else if (qt == 3) {
#pragma unroll
    for (int r = 0; r < 4; ++r) {
      float4 st; st.x = accv[r][0]; st.y = accv[r][1]; st.z = accv[r][2]; st.w = accv[r][3];
      *(float4*)&kB[(n0 + r) * HD + h0] = st;
    }
  }
  __syncthreads();
  if (qt == 0) {
#pragma unroll
    for (int r = 0; r < 4; ++r) {
      float4 p = *(const float4*)&kA[(n0 + r) * HD + h0];
      p.x += accv[r][0]; p.y += accv[r][1]; p.z += accv[r][2]; p.w += accv[r][3];
      *(float4*)&kA[(n0 + r) * HD + h0] = p;
    }
  } else if (qt == 2) {
#pragma unroll
    for (int r = 0; r < 4; ++r) {
      float4 p = *(const float4*)&kB[(n0 + r) * HD + h0];
      p.x += accv[r][0]; p.y += accv[r][1]; p.z += accv[r][2]; p.w += accv[r][3];
      *(float4*)&kB[(n0 + r) * HD + h0] = p;
    }
  }
  __syncthreads();
  {
    float4 a = ((const float4*)kA)[t];   // 4096 floats = 1024 float4, one per thread
    const float4 c = ((const float4*)kB)[t];
    a.x += c.x; a.y += c.y; a.z += c.z; a.w += c.w;
    ((float4*)s_keys)[t] = a;
  }
  __syncthreads();

  // Phase 4: sim[n] — each of 16 waves owns 4 slot rows
  const float qv = s_q[lane];
  const float qn = fmaxf(sqrtf(wsum(qv * qv)), 1e-12f);
#pragma unroll
  for (int r = 0; r < 4; ++r) {
    const int n = (wave << 2) + r;
    const float kv = s_keys[n * HD + lane];
    const float kk = wsum(kv * kv);
    const float kq = wsum(kv * qv);
    if (lane == 0) s_sim[n] = kq / (fmaxf(sqrtf(kk), 1e-12f) * qn);
  }
  __syncthreads();

  // Phase 5+6 fused: every wave redundantly computes the 64-slot softmax
  // in-register (attn for slot `lane` sits at lane `lane`), broadcasts the 4
  // values it needs via shfl, accumulates its ctx partial. One barrier saved.
  {
    const float svv = s_sim[lane];
    const float m = wmax(svv);
    const float e = expf(svv - m);
    const float ssum = wsum(e);
    const float attn_l = e / ssum;
    float c = 0.f;
#pragma unroll
    for (int r = 0; r < 4; ++r) {
      const int n = (wave << 2) + r;
      const float an = __shfl(attn_l, n, 64);
      c = fmaf(an, s_keys[n * HD + lane], c);
    }
    s_part[wave * HD + lane] = c;
  }
  __syncthreads();
  if (wave == 0) {
    float c0 = 0.f, c1 = 0.f, c2 = 0.f, c3 = 0.f;
#pragma unroll
    for (int w = 0; w < 16; w += 4) {
      c0 += s_part[(w + 0) * HD + lane];
      c1 += s_part[(w + 1) * HD + lane];
      c2 += s_part[(w + 2) * HD + lane];
      c3 += s_part[(w + 3) * HD + lane];
    }
    s_ctx[lane] = (c0 + c1) + (c2 + c3);
  }
  __syncthreads();

  // Phase 7: out = ctx @ out_w + out_b (threads 0..127, coalesced out_w)
  if (t < VC) {
    float o0 = 0.f, o1 = 0.f, o2 = 0.f, o3 = 0.f;
#pragma unroll
    for (int h = 0; h < HD; h += 4) {
      o0 = fmaf(s_ctx[h + 0], out_w[(h + 0) * VC + t], o0);
      o1 = fmaf(s_ctx[h + 1], out_w[(h + 1) * VC + t], o1);
      o2 = fmaf(s_ctx[h + 2], out_w[(h + 2) * VC + t], o2);
      o3 = fmaf(s_ctx[h + 3], out_w[(h + 3) * VC + t], o3);
    }
    out[b * VC + t] = out_b[t] + ((o0 + o1) + (o2 + o3));
  }
}

extern "C" void kernel_launch(void* const* d_in, const int* in_sizes, int n_in,
                              void* d_out, int out_size, void* d_ws, size_t ws_size,
                              hipStream_t stream) {
  const int* seq         = (const int*)d_in[0];
  const float* embed_w   = (const float*)d_in[1];
  const float* w1        = (const float*)d_in[2];
  const float* b1        = (const float*)d_in[3];
  const float* w2        = (const float*)d_in[4];
  const float* b2        = (const float*)d_in[5];
  const float* ln_g      = (const float*)d_in[6];
  const float* ln_b      = (const float*)d_in[7];
  const float* slot_keys = (const float*)d_in[8];
  // d_in[9] = slot_vals: unused (reference sets vals = keys)
  const float* gate_w    = (const float*)d_in[10];
  const float* gate_b    = (const float*)d_in[11];
  const float* out_w     = (const float*)d_in[12];
  const float* out_b     = (const float*)d_in[13];
  float* out = (float*)d_out;

  float* HN  = (float*)d_ws;       // 128*64 f32
  float* WSM = HN + VC * HD;       // 128*64 f32

  build_tables<<<VC, 128, 0, stream>>>(embed_w, w1, b1, w2, b2, ln_g, ln_b,
                                       gate_w, gate_b, HN, WSM);
  batch_kernel<<<NB, 1024, 0, stream>>>(seq, HN, WSM, slot_keys, out_w, out_b, out);
}

// Round 4
// 92.053 us; speedup vs baseline: 1.6674x; 1.0173x over previous
//
#include <hip/hip_runtime.h>

#define HD 64      // HIDDEN_DIM
#define VC 128     // VOCAB_SIZE
#define NS 64      // NUM_SLOTS
#define NB 256     // B
#define SL 4096    // L

typedef __attribute__((ext_vector_type(8))) short short8;
typedef __attribute__((ext_vector_type(4))) float f32x4;

// swizzled ushort index into a [row][128] bf16 LDS tile (row stride 256B).
// XOR of bits 3-5 (16B granules) by row&7 spreads stride-256B column accesses
// across 8 distinct 16B slots -> bank-conflict-floor reads AND writes.
#define SWZ(row, col_u) ((((row) * VC) + (col_u)) ^ (((row) & 7) << 3))

__device__ __forceinline__ float wsum(float x) {
#pragma unroll
  for (int o = 32; o > 0; o >>= 1) x += __shfl_xor(x, o, 64);
  return x;
}
__device__ __forceinline__ float wmax(float x) {
#pragma unroll
  for (int o = 32; o > 0; o >>= 1) x = fmaxf(x, __shfl_xor(x, o, 64));
  return x;
}

// Kernel 1: per-vocab tables (unchanged from round 3).
__global__ __launch_bounds__(128) void build_tables(
    const float* __restrict__ embed, const float* __restrict__ w1, const float* __restrict__ b1,
    const float* __restrict__ w2, const float* __restrict__ b2,
    const float* __restrict__ ln_g, const float* __restrict__ ln_b,
    const float* __restrict__ gate_w, const float* __restrict__ gate_b,
    float* __restrict__ HN, float* __restrict__ WSM)
{
  const int v = blockIdx.x, t = threadIdx.x;
  __shared__ float s_e[HD], s_f1[2 * HD], s_hn[HD], s_red[128];

  if (t < HD) s_e[t] = embed[v * HD + t];
  __syncthreads();

  {
    float a0 = 0.f, a1 = 0.f, a2 = 0.f, a3 = 0.f;
#pragma unroll
    for (int h = 0; h < HD; h += 4) {
      a0 = fmaf(s_e[h + 0], w1[(h + 0) * 2 * HD + t], a0);
      a1 = fmaf(s_e[h + 1], w1[(h + 1) * 2 * HD + t], a1);
      a2 = fmaf(s_e[h + 2], w1[(h + 2) * 2 * HD + t], a2);
      a3 = fmaf(s_e[h + 3], w1[(h + 3) * 2 * HD + t], a3);
    }
    s_f1[t] = fmaxf(b1[t] + ((a0 + a1) + (a2 + a3)), 0.f);
  }
  __syncthreads();

  {
    const int col = t & 63;
    const int j0 = (t >> 6) << 6;  // 0 or 64
    float a0 = 0.f, a1 = 0.f, a2 = 0.f, a3 = 0.f;
#pragma unroll
    for (int j = 0; j < 64; j += 4) {
      a0 = fmaf(s_f1[j0 + j + 0], w2[(j0 + j + 0) * HD + col], a0);
      a1 = fmaf(s_f1[j0 + j + 1], w2[(j0 + j + 1) * HD + col], a1);
      a2 = fmaf(s_f1[j0 + j + 2], w2[(j0 + j + 2) * HD + col], a2);
      a3 = fmaf(s_f1[j0 + j + 3], w2[(j0 + j + 3) * HD + col], a3);
    }
    s_red[t] = (a0 + a1) + (a2 + a3);
  }
  __syncthreads();

  if (t < HD) {
    float x = s_e[t] + b2[t] + s_red[t] + s_red[t + 64];
    float mu = wsum(x) * (1.f / 64.f);
    float d = x - mu;
    float var = wsum(d * d) * (1.f / 64.f);
    float hn = d * rsqrtf(var + 1e-5f) * ln_g[t] + ln_b[t];
    s_hn[t] = hn;
    HN[v * HD + t] = hn;
  }
  __syncthreads();

  {
    const int col = t & 63;
    const int hh0 = (t >> 6) << 5;  // 0 or 32
    float a0 = 0.f, a1 = 0.f, a2 = 0.f, a3 = 0.f;
#pragma unroll
    for (int h = 0; h < 32; h += 4) {
      a0 = fmaf(s_hn[hh0 + h + 0], gate_w[(hh0 + h + 0) * NS + col], a0);
      a1 = fmaf(s_hn[hh0 + h + 1], gate_w[(hh0 + h + 1) * NS + col], a1);
      a2 = fmaf(s_hn[hh0 + h + 2], gate_w[(hh0 + h + 2) * NS + col], a2);
      a3 = fmaf(s_hn[hh0 + h + 3], gate_w[(hh0 + h + 3) * NS + col], a3);
    }
    s_red[t] = (a0 + a1) + (a2 + a3);
  }
  __syncthreads();

  if (t < NS) {
    float g = gate_b[t] + s_red[t] + s_red[t + 64];
    float m = wmax(g);
    float e = expf(g - m);
    float s = wsum(e);
    WSM[v * NS + t] = e / s;
  }
}

// Kernel 2: one block per batch, 1024 threads (16 waves).
// keys = slot_keys + (cnt*WSM)^T @ HN computed via split-bf16 MFMA:
//   A[n][v] = Wt (cnt-scaled WSM transposed), B[v][h] via Ht = H^T; each value
//   split x = hi + lo (bf16 pair), 4 mfma products -> ~f32 precision.
// Each wave owns one 16x16 output tile with FULL k=128 -> no combine phase.
__global__ __launch_bounds__(1024) void batch_kernel(
    const int* __restrict__ seq, const float* __restrict__ HN, const float* __restrict__ WSM,
    const float* __restrict__ slot_keys, const float* __restrict__ out_w,
    const float* __restrict__ out_b, float* __restrict__ out)
{
  const int b = blockIdx.x, t = threadIdx.x;
  const int lane = t & 63, wave = t >> 6;

  __shared__ int s_cnt[VC];
  __shared__ int s_qtok;
  __align__(16) __shared__ unsigned short s_wt_hi[NS * VC];  // 16 KB: A hi, swizzled
  __align__(16) __shared__ unsigned short s_wt_lo[NS * VC];  // 16 KB: A lo
  __align__(16) __shared__ unsigned short s_ht_hi[HD * VC];  // 16 KB: B^T hi
  __align__(16) __shared__ unsigned short s_ht_lo[HD * VC];  // 16 KB: B^T lo
  __align__(16) __shared__ float s_keys[NS * HD];            // 16 KB
  __align__(16) __shared__ float s_part[16 * HD];            // 4 KB
  __shared__ float s_q[HD], s_sim[NS], s_ctx[HD];

  const int col64 = t & 63;   // n-index for Wt staging, h-index for Ht staging
  const int vb = t >> 6;      // vocab block: this thread stages v in [8vb, 8vb+8)

  // MFMA tile assignment: wave -> 16x16 output tile; lane -> fragment coords.
  const int n0 = (wave & 3) << 4;
  const int h0 = (wave >> 2) << 4;
  const int fr = lane & 15;   // frag row (A) / col (B) / D col
  const int fg = lane >> 4;   // k-group

  // ---- Issue ALL global loads up front (latency overlap) ----
  const int* sb = seq + b * SL;
  const int4 sv = ((const int4*)sb)[t];          // tokens 4t .. 4t+3

  float wreg[8], hreg[8];
#pragma unroll
  for (int j = 0; j < 8; ++j) {
    wreg[j] = WSM[(vb * 8 + j) * NS + col64];    // W[v][n], coalesced per j
    hreg[j] = HN[(vb * 8 + j) * HD + col64];     // H[v][h], coalesced per j
  }
  float skv[4];
#pragma unroll
  for (int r = 0; r < 4; ++r)
    skv[r] = slot_keys[(n0 + fg * 4 + r) * HD + h0 + fr];  // mfma C-init

  if (t < VC) s_cnt[t] = 0;
  __syncthreads();

  // ---- Phase 1: histogram ----
  atomicAdd(&s_cnt[sv.x], 1);
  atomicAdd(&s_cnt[sv.y], 1);
  atomicAdd(&s_cnt[sv.z], 1);
  if (t != 1023) atomicAdd(&s_cnt[sv.w], 1);
  else s_qtok = sv.w;                            // seq[b, L-1] excluded
  __syncthreads();                               // cnt + qtok final

  // ---- Phase 2: cnt-scale W, split-bf16, transposed+swizzled stage ----
  {
    short8 vwhi, vwlo, vhhi, vhlo;
#pragma unroll
    for (int j = 0; j < 8; ++j) {
      const float c = (float)s_cnt[vb * 8 + j];
      const float w = wreg[j] * c;
      const unsigned int wb_ = __float_as_uint(w);
      vwhi[j] = (short)(wb_ >> 16);
      const float wr = w - __uint_as_float(wb_ & 0xffff0000u);
      vwlo[j] = (short)(__float_as_uint(wr) >> 16);

      const float h = hreg[j];
      const unsigned int hb_ = __float_as_uint(h);
      vhhi[j] = (short)(hb_ >> 16);
      const float hr = h - __uint_as_float(hb_ & 0xffff0000u);
      vhlo[j] = (short)(__float_as_uint(hr) >> 16);
    }
    const int idx = SWZ(col64, vb * 8);          // multiple of 8 -> 16B aligned
    *(short8*)&s_wt_hi[idx] = vwhi;
    *(short8*)&s_wt_lo[idx] = vwlo;
    *(short8*)&s_ht_hi[idx] = vhhi;
    *(short8*)&s_ht_lo[idx] = vhlo;
  }
  // q row: the wave holding vocab block qtok>>3 has HN[qtok][col64] in regs.
  {
    const int qtok = s_qtok;
    if (vb == (qtok >> 3)) {
      const int qj = qtok & 7;
      float qv = hreg[0];
#pragma unroll
      for (int j = 1; j < 8; ++j) if (qj == j) qv = hreg[j];
      s_q[col64] = qv;
    }
  }
  __syncthreads();                               // tables staged

  // ---- Phase 3: MFMA GEMM, full k=128 per wave, 4 k-chunks x 4 products ----
  {
    f32x4 acc = {skv[0], skv[1], skv[2], skv[3]};
#pragma unroll
    for (int kc = 0; kc < 4; ++kc) {
      const int au = SWZ(n0 + fr, fg * 8 + kc * 32);
      const int bu = SWZ(h0 + fr, fg * 8 + kc * 32);
      const short8 ahi = *(const short8*)&s_wt_hi[au];
      const short8 alo = *(const short8*)&s_wt_lo[au];
      const short8 bhi = *(const short8*)&s_ht_hi[bu];
      const short8 blo = *(const short8*)&s_ht_lo[bu];
      acc = __builtin_amdgcn_mfma_f32_16x16x32_bf16(ahi, bhi, acc, 0, 0, 0);
      acc = __builtin_amdgcn_mfma_f32_16x16x32_bf16(ahi, blo, acc, 0, 0, 0);
      acc = __builtin_amdgcn_mfma_f32_16x16x32_bf16(alo, bhi, acc, 0, 0, 0);
      acc = __builtin_amdgcn_mfma_f32_16x16x32_bf16(alo, blo, acc, 0, 0, 0);
    }
    // D layout: col = lane&15 (h), row = (lane>>4)*4 + r (n)  [m89-verified]
#pragma unroll
    for (int r = 0; r < 4; ++r)
      s_keys[(n0 + fg * 4 + r) * HD + h0 + fr] = acc[r];
  }
  __syncthreads();

  // ---- Phase 4: sim[n] — each of 16 waves owns 4 slot rows ----
  const float qv = s_q[lane];
  const float qn = fmaxf(sqrtf(wsum(qv * qv)), 1e-12f);
#pragma unroll
  for (int r = 0; r < 4; ++r) {
    const int n = (wave << 2) + r;
    const float kv = s_keys[n * HD + lane];
    const float kk = wsum(kv * kv);
    const float kq = wsum(kv * qv);
    if (lane == 0) s_sim[n] = kq / (fmaxf(sqrtf(kk), 1e-12f) * qn);
  }
  __syncthreads();

  // ---- Phase 5+6 fused: redundant in-register softmax + ctx partials ----
  {
    const float svv = s_sim[lane];
    const float m = wmax(svv);
    const float e = expf(svv - m);
    const float ssum = wsum(e);
    const float attn_l = e / ssum;
    float c = 0.f;
#pragma unroll
    for (int r = 0; r < 4; ++r) {
      const int n = (wave << 2) + r;
      const float an = __shfl(attn_l, n, 64);
      c = fmaf(an, s_keys[n * HD + lane], c);
    }
    s_part[wave * HD + lane] = c;
  }
  __syncthreads();
  if (wave == 0) {
    float c0 = 0.f, c1 = 0.f, c2 = 0.f, c3 = 0.f;
#pragma unroll
    for (int w = 0; w < 16; w += 4) {
      c0 += s_part[(w + 0) * HD + lane];
      c1 += s_part[(w + 1) * HD + lane];
      c2 += s_part[(w + 2) * HD + lane];
      c3 += s_part[(w + 3) * HD + lane];
    }
    s_ctx[lane] = (c0 + c1) + (c2 + c3);
  }
  __syncthreads();

  // ---- Phase 7: out = ctx @ out_w + out_b ----
  if (t < VC) {
    float o0 = 0.f, o1 = 0.f, o2 = 0.f, o3 = 0.f;
#pragma unroll
    for (int h = 0; h < HD; h += 4) {
      o0 = fmaf(s_ctx[h + 0], out_w[(h + 0) * VC + t], o0);
      o1 = fmaf(s_ctx[h + 1], out_w[(h + 1) * VC + t], o1);
      o2 = fmaf(s_ctx[h + 2], out_w[(h + 2) * VC + t], o2);
      o3 = fmaf(s_ctx[h + 3], out_w[(h + 3) * VC + t], o3);
    }
    out[b * VC + t] = out_b[t] + ((o0 + o1) + (o2 + o3));
  }
}

extern "C" void kernel_launch(void* const* d_in, const int* in_sizes, int n_in,
                              void* d_out, int out_size, void* d_ws, size_t ws_size,
                              hipStream_t stream) {
  const int* seq         = (const int*)d_in[0];
  const float* embed_w   = (const float*)d_in[1];
  const float* w1        = (const float*)d_in[2];
  const float* b1        = (const float*)d_in[3];
  const float* w2        = (const float*)d_in[4];
  const float* b2        = (const float*)d_in[5];
  const float* ln_g      = (const float*)d_in[6];
  const float* ln_b      = (const float*)d_in[7];
  const float* slot_keys = (const float*)d_in[8];
  // d_in[9] = slot_vals: unused (reference sets vals = keys)
  const float* gate_w    = (const float*)d_in[10];
  const float* gate_b    = (const float*)d_in[11];
  const float* out_w     = (const float*)d_in[12];
  const float* out_b     = (const float*)d_in[13];
  float* out = (float*)d_out;

  float* HN  = (float*)d_ws;       // 128*64 f32
  float* WSM = HN + VC * HD;       // 128*64 f32

  build_tables<<<VC, 128, 0, stream>>>(embed_w, w1, b1, w2, b2, ln_g, ln_b,
                                       gate_w, gate_b, HN, WSM);
  batch_kernel<<<NB, 1024, 0, stream>>>(seq, HN, WSM, slot_keys, out_w, out_b, out);
}

// Round 5
// 92.017 us; speedup vs baseline: 1.6681x; 1.0004x over previous
//
#include <hip/hip_runtime.h>

#define HD 64      // HIDDEN_DIM
#define VC 128     // VOCAB_SIZE
#define NS 64      // NUM_SLOTS
#define NB 256     // B
#define SL 4096    // L

typedef __attribute__((ext_vector_type(8))) short short8;
typedef __attribute__((ext_vector_type(4))) float f32x4;

// swizzled ushort index into a [row][128] bf16 tile (row stride 256B).
// XOR of bits 3-5 (16B granules) by row&7 spreads stride-256B column accesses
// across 8 distinct 16B slots -> bank-conflict-floor reads AND writes.
#define SWZ(row, col_u) ((((row) * VC) + (col_u)) ^ (((row) & 7) << 3))

__device__ __forceinline__ float wsum(float x) {
#pragma unroll
  for (int o = 32; o > 0; o >>= 1) x += __shfl_xor(x, o, 64);
  return x;
}
__device__ __forceinline__ float wmax(float x) {
#pragma unroll
  for (int o = 32; o > 0; o >>= 1) x = fmaxf(x, __shfl_xor(x, o, 64));
  return x;
}

// Kernel 1: per-vocab tables, emitted in k2-ready form:
//   WSMT[n][v] = softmax_n(HN[v] @ gate_w + gate_b)   (f32, transposed)
//   HtHi/HtLo[SWZ(h,v)] = split-bf16 of HN[v][h]      (pre-swizzled blob)
// HN itself is never materialized in f32 (k2 reconstructs q = hi+lo).
__global__ __launch_bounds__(128) void build_tables(
    const float* __restrict__ embed, const float* __restrict__ w1, const float* __restrict__ b1,
    const float* __restrict__ w2, const float* __restrict__ b2,
    const float* __restrict__ ln_g, const float* __restrict__ ln_b,
    const float* __restrict__ gate_w, const float* __restrict__ gate_b,
    float* __restrict__ WSMT, unsigned short* __restrict__ HtHi,
    unsigned short* __restrict__ HtLo)
{
  const int v = blockIdx.x, t = threadIdx.x;
  __shared__ float s_e[HD], s_f1[2 * HD], s_hn[HD], s_red[128];

  if (t < HD) s_e[t] = embed[v * HD + t];
  __syncthreads();

  // ff1 = relu(e @ w1 + b1), one output per thread (128 outputs)
  {
    float a0 = 0.f, a1 = 0.f, a2 = 0.f, a3 = 0.f;
#pragma unroll
    for (int h = 0; h < HD; h += 4) {
      a0 = fmaf(s_e[h + 0], w1[(h + 0) * 2 * HD + t], a0);
      a1 = fmaf(s_e[h + 1], w1[(h + 1) * 2 * HD + t], a1);
      a2 = fmaf(s_e[h + 2], w1[(h + 2) * 2 * HD + t], a2);
      a3 = fmaf(s_e[h + 3], w1[(h + 3) * 2 * HD + t], a3);
    }
    s_f1[t] = fmaxf(b1[t] + ((a0 + a1) + (a2 + a3)), 0.f);
  }
  __syncthreads();

  // ff2: output col = t&63; j-range [0,128) split across the two halves
  {
    const int col = t & 63;
    const int j0 = (t >> 6) << 6;  // 0 or 64
    float a0 = 0.f, a1 = 0.f, a2 = 0.f, a3 = 0.f;
#pragma unroll
    for (int j = 0; j < 64; j += 4) {
      a0 = fmaf(s_f1[j0 + j + 0], w2[(j0 + j + 0) * HD + col], a0);
      a1 = fmaf(s_f1[j0 + j + 1], w2[(j0 + j + 1) * HD + col], a1);
      a2 = fmaf(s_f1[j0 + j + 2], w2[(j0 + j + 2) * HD + col], a2);
      a3 = fmaf(s_f1[j0 + j + 3], w2[(j0 + j + 3) * HD + col], a3);
    }
    s_red[t] = (a0 + a1) + (a2 + a3);
  }
  __syncthreads();

  // residual + layernorm (wave 0); emit split-bf16 Ht directly
  if (t < HD) {
    float x = s_e[t] + b2[t] + s_red[t] + s_red[t + 64];
    float mu = wsum(x) * (1.f / 64.f);
    float d = x - mu;
    float var = wsum(d * d) * (1.f / 64.f);
    float hn = d * rsqrtf(var + 1e-5f) * ln_g[t] + ln_b[t];
    s_hn[t] = hn;
    const unsigned int hb_ = __float_as_uint(hn);
    const unsigned short hi = (unsigned short)(hb_ >> 16);
    const float rem = hn - __uint_as_float(hb_ & 0xffff0000u);
    const unsigned short lo = (unsigned short)(__float_as_uint(rem) >> 16);
    const int idx = SWZ(t, v);
    HtHi[idx] = hi;
    HtLo[idx] = lo;
  }
  __syncthreads();

  // gate logits: col = t&63; h-range [0,64) split across the two halves
  {
    const int col = t & 63;
    const int hh0 = (t >> 6) << 5;  // 0 or 32
    float a0 = 0.f, a1 = 0.f, a2 = 0.f, a3 = 0.f;
#pragma unroll
    for (int h = 0; h < 32; h += 4) {
      a0 = fmaf(s_hn[hh0 + h + 0], gate_w[(hh0 + h + 0) * NS + col], a0);
      a1 = fmaf(s_hn[hh0 + h + 1], gate_w[(hh0 + h + 1) * NS + col], a1);
      a2 = fmaf(s_hn[hh0 + h + 2], gate_w[(hh0 + h + 2) * NS + col], a2);
      a3 = fmaf(s_hn[hh0 + h + 3], gate_w[(hh0 + h + 3) * NS + col], a3);
    }
    s_red[t] = (a0 + a1) + (a2 + a3);
  }
  __syncthreads();

  // gate softmax over slots (wave 0); store transposed
  if (t < NS) {
    float g = gate_b[t] + s_red[t] + s_red[t + 64];
    float m = wmax(g);
    float e = expf(g - m);
    float s = wsum(e);
    WSMT[t * VC + v] = e / s;
  }
}

// Kernel 2: one block per batch, 1024 threads (16 waves).
// keys = slot_keys + (cnt*WSM)^T @ HN via split-bf16 MFMA (round-4 verified).
// ALL global inputs prefetched in one prologue burst; out_w staged to LDS so
// the post-barrier tail has zero global-load latency.
__global__ __launch_bounds__(1024) void batch_kernel(
    const int* __restrict__ seq, const float* __restrict__ WSMT,
    const unsigned short* __restrict__ HtHi, const unsigned short* __restrict__ HtLo,
    const float* __restrict__ slot_keys, const float* __restrict__ out_w,
    const float* __restrict__ out_b, float* __restrict__ out)
{
  const int b = blockIdx.x, t = threadIdx.x;
  const int lane = t & 63, wave = t >> 6;

  __shared__ int s_cnt[VC];
  __shared__ int s_qtok;
  __align__(16) __shared__ unsigned short s_wt_hi[NS * VC];  // 16 KB: A hi, swizzled
  __align__(16) __shared__ unsigned short s_wt_lo[NS * VC];  // 16 KB: A lo
  __align__(16) __shared__ unsigned short s_ht_hi[HD * VC];  // 16 KB: B^T hi (blob copy)
  __align__(16) __shared__ unsigned short s_ht_lo[HD * VC];  // 16 KB: B^T lo
  __align__(16) __shared__ float s_ow[HD * VC];              // 32 KB: out_w
  __align__(16) __shared__ float s_keys[NS * HD];            // 16 KB
  __align__(16) __shared__ float s_part[16 * HD];            // 4 KB
  __shared__ float s_q[HD], s_sim[NS], s_ctx[HD];

  // W staging map: thread -> (slot row wn, vocab octet wv8); coalesced global read.
  const int wn = t >> 4;
  const int wv8 = (t & 15) << 3;

  // MFMA tile assignment: wave -> 16x16 output tile; lane -> fragment coords.
  const int n0 = (wave & 3) << 4;
  const int h0 = (wave >> 2) << 4;
  const int fr = lane & 15;   // frag row (A) / col (B) / D col
  const int fg = lane >> 4;   // k-group

  // ---- Prologue: issue ALL global loads at once (one HBM latency total) ----
  const int4 sv = ((const int4*)(seq + b * SL))[t];           // tokens 4t..4t+3
  const float4 wt0 = *(const float4*)&WSMT[wn * VC + wv8];    // W^T row chunk
  const float4 wt1 = *(const float4*)&WSMT[wn * VC + wv8 + 4];
  const short8 hhi = ((const short8*)HtHi)[t];                // Ht blobs, linear
  const short8 hlo = ((const short8*)HtLo)[t];
  const float4 ow0 = ((const float4*)out_w)[t];               // out_w, linear
  const float4 ow1 = ((const float4*)out_w)[t + 1024];
  const float ob = (t < VC) ? out_b[t] : 0.f;
  float skv[4];
#pragma unroll
  for (int r = 0; r < 4; ++r)
    skv[r] = slot_keys[(n0 + fg * 4 + r) * HD + h0 + fr];     // mfma C-init

  if (t < VC) s_cnt[t] = 0;
  __syncthreads();

  // ---- Phase 1: histogram + cnt-independent LDS staging (Ht, out_w) ----
  atomicAdd(&s_cnt[sv.x], 1);
  atomicAdd(&s_cnt[sv.y], 1);
  atomicAdd(&s_cnt[sv.z], 1);
  if (t != 1023) atomicAdd(&s_cnt[sv.w], 1);
  else s_qtok = sv.w;                            // seq[b, L-1] excluded
  ((short8*)s_ht_hi)[t] = hhi;
  ((short8*)s_ht_lo)[t] = hlo;
  ((float4*)s_ow)[t] = ow0;
  ((float4*)s_ow)[t + 1024] = ow1;
  __syncthreads();                               // cnt + qtok + Ht + ow ready

  // ---- Phase 2: cnt-scale W^T, split-bf16, swizzled stage; reconstruct q ----
  {
    const int4 c0 = *(const int4*)&s_cnt[wv8];
    const int4 c1 = *(const int4*)&s_cnt[wv8 + 4];
    float wf[8] = {wt0.x, wt0.y, wt0.z, wt0.w, wt1.x, wt1.y, wt1.z, wt1.w};
    const int cc[8] = {c0.x, c0.y, c0.z, c0.w, c1.x, c1.y, c1.z, c1.w};
    short8 vhi, vlo;
#pragma unroll
    for (int j = 0; j < 8; ++j) {
      const float w = wf[j] * (float)cc[j];
      const unsigned int wb_ = __float_as_uint(w);
      vhi[j] = (short)(wb_ >> 16);
      const float wr = w - __uint_as_float(wb_ & 0xffff0000u);
      vlo[j] = (short)(__float_as_uint(wr) >> 16);
    }
    const int idx = SWZ(wn, wv8);                // 16B-aligned
    *(short8*)&s_wt_hi[idx] = vhi;
    *(short8*)&s_wt_lo[idx] = vlo;
  }
  if (t < HD) {
    const int qtok = s_qtok;
    const unsigned int hi = s_ht_hi[SWZ(t, qtok)];
    const unsigned int lo = s_ht_lo[SWZ(t, qtok)];
    s_q[t] = __uint_as_float(hi << 16) + __uint_as_float(lo << 16);
  }
  __syncthreads();                               // Wt staged

  // ---- Phase 3: MFMA GEMM, full k=128 per wave (round-4 verified layout) ----
  {
    f32x4 acc = {skv[0], skv[1], skv[2], skv[3]};
#pragma unroll
    for (int kc = 0; kc < 4; ++kc) {
      const int au = SWZ(n0 + fr, fg * 8 + kc * 32);
      const int bu = SWZ(h0 + fr, fg * 8 + kc * 32);
      const short8 ahi = *(const short8*)&s_wt_hi[au];
      const short8 alo = *(const short8*)&s_wt_lo[au];
      const short8 bhi = *(const short8*)&s_ht_hi[bu];
      const short8 blo = *(const short8*)&s_ht_lo[bu];
      acc = __builtin_amdgcn_mfma_f32_16x16x32_bf16(ahi, bhi, acc, 0, 0, 0);
      acc = __builtin_amdgcn_mfma_f32_16x16x32_bf16(ahi, blo, acc, 0, 0, 0);
      acc = __builtin_amdgcn_mfma_f32_16x16x32_bf16(alo, bhi, acc, 0, 0, 0);
      acc = __builtin_amdgcn_mfma_f32_16x16x32_bf16(alo, blo, acc, 0, 0, 0);
    }
    // D layout: col = lane&15 (h), row = (lane>>4)*4 + r (n)  [m89-verified]
#pragma unroll
    for (int r = 0; r < 4; ++r)
      s_keys[(n0 + fg * 4 + r) * HD + h0 + fr] = acc[r];
  }
  __syncthreads();

  // ---- Phase 4: sim[n] — each of 16 waves owns 4 slot rows ----
  const float qv = s_q[lane];
  const float qn = fmaxf(sqrtf(wsum(qv * qv)), 1e-12f);
#pragma unroll
  for (int r = 0; r < 4; ++r) {
    const int n = (wave << 2) + r;
    const float kv = s_keys[n * HD + lane];
    const float kk = wsum(kv * kv);
    const float kq = wsum(kv * qv);
    if (lane == 0) s_sim[n] = kq / (fmaxf(sqrtf(kk), 1e-12f) * qn);
  }
  __syncthreads();

  // ---- Phase 5+6 fused: redundant in-register softmax + ctx partials ----
  {
    const float svv = s_sim[lane];
    const float m = wmax(svv);
    const float e = expf(svv - m);
    const float ssum = wsum(e);
    const float attn_l = e / ssum;
    float c = 0.f;
#pragma unroll
    for (int r = 0; r < 4; ++r) {
      const int n = (wave << 2) + r;
      const float an = __shfl(attn_l, n, 64);
      c = fmaf(an, s_keys[n * HD + lane], c);
    }
    s_part[wave * HD + lane] = c;
  }
  __syncthreads();
  if (wave == 0) {
    float c0 = 0.f, c1 = 0.f, c2 = 0.f, c3 = 0.f;
#pragma unroll
    for (int w = 0; w < 16; w += 4) {
      c0 += s_part[(w + 0) * HD + lane];
      c1 += s_part[(w + 1) * HD + lane];
      c2 += s_part[(w + 2) * HD + lane];
      c3 += s_part[(w + 3) * HD + lane];
    }
    s_ctx[lane] = (c0 + c1) + (c2 + c3);
  }
  __syncthreads();

  // ---- Phase 7: out = ctx @ out_w + out_b, entirely from LDS ----
  if (t < VC) {
    float o0 = 0.f, o1 = 0.f, o2 = 0.f, o3 = 0.f;
#pragma unroll
    for (int h = 0; h < HD; h += 4) {
      o0 = fmaf(s_ctx[h + 0], s_ow[(h + 0) * VC + t], o0);
      o1 = fmaf(s_ctx[h + 1], s_ow[(h + 1) * VC + t], o1);
      o2 = fmaf(s_ctx[h + 2], s_ow[(h + 2) * VC + t], o2);
      o3 = fmaf(s_ctx[h + 3], s_ow[(h + 3) * VC + t], o3);
    }
    out[b * VC + t] = ob + ((o0 + o1) + (o2 + o3));
  }
}

extern "C" void kernel_launch(void* const* d_in, const int* in_sizes, int n_in,
                              void* d_out, int out_size, void* d_ws, size_t ws_size,
                              hipStream_t stream) {
  const int* seq         = (const int*)d_in[0];
  const float* embed_w   = (const float*)d_in[1];
  const float* w1        = (const float*)d_in[2];
  const float* b1        = (const float*)d_in[3];
  const float* w2        = (const float*)d_in[4];
  const float* b2        = (const float*)d_in[5];
  const float* ln_g      = (const float*)d_in[6];
  const float* ln_b      = (const float*)d_in[7];
  const float* slot_keys = (const float*)d_in[8];
  // d_in[9] = slot_vals: unused (reference sets vals = keys)
  const float* gate_w    = (const float*)d_in[10];
  const float* gate_b    = (const float*)d_in[11];
  const float* out_w     = (const float*)d_in[12];
  const float* out_b     = (const float*)d_in[13];
  float* out = (float*)d_out;

  float* WSMT = (float*)d_ws;                       // 64*128 f32 (32 KB)
  unsigned short* HtHi = (unsigned short*)(WSMT + NS * VC);  // 16 KB blob
  unsigned short* HtLo = HtHi + HD * VC;                     // 16 KB blob

  build_tables<<<VC, 128, 0, stream>>>(embed_w, w1, b1, w2, b2, ln_g, ln_b,
                                       gate_w, gate_b, WSMT, HtHi, HtLo);
  batch_kernel<<<NB, 1024, 0, stream>>>(seq, WSMT, HtHi, HtLo, slot_keys,
                                        out_w, out_b, out);
}